// Round 12
// baseline (376.153 us; speedup 1.0000x reference)
//
#include <hip/hip_runtime.h>
#include <hip/hip_bf16.h>
#include <stdint.h>

// out = x @ W'^T + bias, W' = FWHT(W rows)/sqrt(n)  (H symmetric, folded into W)
// x (4,2048,8192) f32 -> M=8192, K=8192 ; W (2048,8192) -> N=2048 ; out f32.

#define M_TOTAL 8192
#define K_TOTAL 8192
#define N_TOTAL 2048
#define D_IN 8192

typedef __attribute__((ext_vector_type(8))) short short8;
typedef __attribute__((ext_vector_type(4))) float f32x4;
typedef __attribute__((ext_vector_type(16))) float f32x16;

typedef __attribute__((address_space(1))) void void_g;
typedef __attribute__((address_space(3))) void void_l;
typedef __attribute__((address_space(3))) short lds_s3;

__device__ __forceinline__ short f2bf(float f) {
  __hip_bfloat16 h = __float2bfloat16(f);
  return *reinterpret_cast<short*>(&h);
}

// ---------------- kernel 1: x fp32 -> bf16 ----------------
__global__ void cvt_x_kernel(const float* __restrict__ x, short* __restrict__ xb, long n) {
  long stride = (long)gridDim.x * blockDim.x * 8;
  for (long i = ((long)blockIdx.x * blockDim.x + threadIdx.x) * 8; i < n; i += stride) {
    float4 v0 = *(const float4*)(x + i);
    float4 v1 = *(const float4*)(x + i + 4);
    short8 o;
    o[0] = f2bf(v0.x); o[1] = f2bf(v0.y); o[2] = f2bf(v0.z); o[3] = f2bf(v0.w);
    o[4] = f2bf(v1.x); o[5] = f2bf(v1.y); o[6] = f2bf(v1.z); o[7] = f2bf(v1.w);
    *(short8*)(xb + i) = o;
  }
}

// ---------------- kernel 2: W' = FWHT(W rows) / sqrt(n), bf16 ----------------
__global__ void fwht_w_kernel(const float* __restrict__ W, short* __restrict__ Wh) {
  __shared__ float buf[D_IN];
  const int row = blockIdx.x;
  const float* src = W + (long)row * D_IN;
  for (int i = threadIdx.x; i < D_IN / 4; i += blockDim.x)
    ((float4*)buf)[i] = ((const float4*)src)[i];
  for (int h = 1; h < D_IN; h <<= 1) {
    __syncthreads();
    for (int p = threadIdx.x; p < D_IN / 2; p += blockDim.x) {
      int i = ((p & ~(h - 1)) << 1) | (p & (h - 1));
      float a = buf[i], b = buf[i + h];
      buf[i] = a + b;
      buf[i + h] = a - b;
    }
  }
  __syncthreads();
  const float s = 0.011048543456039806f; // 1/sqrt(8192)
  short* dst = Wh + (long)row * D_IN;
  for (int i = threadIdx.x; i < D_IN; i += blockDim.x)
    dst[i] = f2bf(buf[i] * s);
}

// ---------------- kernel 3: 256x256, BK=32, free-run 4-ring, 32x32x16 MFMA ------
// R10/R11 structure (coalesced XOR-swizzled staging, 4-deep ring, ONE fused
// {vmcnt(4); s_barrier} per K-tile, counted lgkm ledger) -- 1127-1180 TF, 51%.
// R12 change: mfma_f32_16x16x32 -> mfma_f32_32x32x16 (2495 vs 2075 TF ceiling:
// MFMA floor 1242 -> 1032 cy/tile; halves MFMA instruction count). LDS layout
// UNCHANGED: per-quarter-wave analysis shows a 32x32 frag read (quarter = 16
// consecutive rows x one 16B chunk) has the same 2-way-free bank pattern under
// slot ^= ((row>>1)&3) as the 16x16 reads measured at 0 conflicts. Fragment
// addressing needs 2 addr regs per operand (ks0: chunks {0,1}; ks1: {2,3} --
// swizzle makes the +2-chunk step non-uniform). Per wave-tile 128x64: blocks
// (mblk 0..3) x (nblk 0..1), acc = 8 x f32x16. C/D map (m74/m101): col=l&31,
// row=(reg&3)+8*(reg>>2)+4*(l>>5). Ledger identical: 12 b128 reads in 4/4/4
// groups {am01, bn, am23}; entry lgkm(4) -> am01+bn ready; mid lgkm(4) after
// issuing next am01 -> am23 ready.
#define NKT 256 // K-tiles of 32

#define ABUF(b) ((b) * 8192)           // shorts (staging)
#define BBUF(b) (32768 + (b) * 8192)   // shorts (staging)

#define SBAR __builtin_amdgcn_sched_barrier(0)
#define BAR __builtin_amdgcn_s_barrier()
#define FEN4 do { SBAR; asm volatile("s_waitcnt vmcnt(4)"); BAR; } while (0)
#define FEN0 do { SBAR; asm volatile("s_waitcnt vmcnt(0)"); BAR; } while (0)
#define FNOP do { } while (0)

// stage one K-tile (A + B, 4 x global_load_lds w16 per thread)
#define STAGET(PB, KOFF)                                                                          \
  __builtin_amdgcn_global_load_lds((void_g*)(aLo + (KOFF)),                                       \
                                   (void_l*)&lds[ABUF(PB) + sdst], 16, 0, 0);                     \
  __builtin_amdgcn_global_load_lds((void_g*)(aHi + (KOFF)),                                       \
                                   (void_l*)&lds[ABUF(PB) + sdst + 4096], 16, 0, 0);              \
  __builtin_amdgcn_global_load_lds((void_g*)(bLo + (KOFF)),                                       \
                                   (void_l*)&lds[BBUF(PB) + sdst], 16, 0, 0);                     \
  __builtin_amdgcn_global_load_lds((void_g*)(bHi + (KOFF)),                                       \
                                   (void_l*)&lds[BBUF(PB) + sdst + 4096], 16, 0, 0);

#define DSR(dst, ADDR, IMM)                                                                       \
  asm volatile("ds_read_b128 %0, %1 offset:%2" : "=v"(dst) : "v"(ADDR), "i"(IMM))

// read groups for buffer NB (byte immediates: NB*16384 + mblk|nblk * 2048)
#define RD_AM01(NB)                                                                               \
  DSR(am[0][0], aAd0, (NB) * 16384 + 0);    DSR(am[0][1], aAd1, (NB) * 16384 + 0);                \
  DSR(am[1][0], aAd0, (NB) * 16384 + 2048); DSR(am[1][1], aAd1, (NB) * 16384 + 2048);
#define RD_BN(NB)                                                                                 \
  DSR(bn[0][0], bAd0, (NB) * 16384 + 0);    DSR(bn[0][1], bAd1, (NB) * 16384 + 0);                \
  DSR(bn[1][0], bAd0, (NB) * 16384 + 2048); DSR(bn[1][1], bAd1, (NB) * 16384 + 2048);
#define RD_AM23(NB)                                                                               \
  DSR(am[2][0], aAd0, (NB) * 16384 + 4096); DSR(am[2][1], aAd1, (NB) * 16384 + 4096);             \
  DSR(am[3][0], aAd0, (NB) * 16384 + 6144); DSR(am[3][1], aAd1, (NB) * 16384 + 6144);

// 8 MFMAs: blocks (MB0, MB0+1) x (nb 0,1), ks outer for dep spacing
#define MFQ(MB0)                                                                                  \
  __builtin_amdgcn_s_setprio(1);                                                                  \
  _Pragma("unroll") for (int ks = 0; ks < 2; ++ks) {                                              \
    _Pragma("unroll") for (int mb = 0; mb < 2; ++mb) {                                            \
      _Pragma("unroll") for (int nb = 0; nb < 2; ++nb)                                            \
          acc[(MB0) + mb][nb] = __builtin_amdgcn_mfma_f32_32x32x16_bf16(                          \
              am[(MB0) + mb][ks], bn[nb][ks], acc[(MB0) + mb][nb], 0, 0, 0);                      \
    }                                                                                             \
  }                                                                                               \
  __builtin_amdgcn_s_setprio(0);

// one K-tile. DOSTG: stage tile t+3 into slot PB. DOPRE: issue next-tile reads
// (buffer NB). FEN: end fence (FEN4 / FEN0 / FNOP).
#define KT(DOSTG, PB, KOFF, DOPRE, NB, FEN)                                                       \
  {                                                                                               \
    asm volatile("s_waitcnt lgkmcnt(4)");                                                         \
    SBAR;                                                                                         \
    MFQ(0);                                                                                       \
    SBAR;                                                                                         \
    if (DOSTG) { STAGET(PB, KOFF); }                                                              \
    if (DOPRE) { RD_AM01(NB); }                                                                   \
    SBAR;                                                                                         \
    if (DOPRE) { asm volatile("s_waitcnt lgkmcnt(4)"); }                                          \
    else       { asm volatile("s_waitcnt lgkmcnt(0)"); }                                          \
    SBAR;                                                                                         \
    MFQ(2);                                                                                       \
    SBAR;                                                                                         \
    if (DOPRE) { RD_BN(NB); RD_AM23(NB); }                                                        \
    SBAR;                                                                                         \
    FEN;                                                                                          \
  }

__global__ __launch_bounds__(512, 2) void gemm_kernel(const short* __restrict__ A,
                                                      const short* __restrict__ B,
                                                      const float* __restrict__ bias,
                                                      float* __restrict__ C) {
  __shared__ __attribute__((aligned(16))) short lds[65536]; // 128 KiB

  const int tid = threadIdx.x;
  const int l = tid & 63;
  const int w = tid >> 6;
  const int wm = w >> 2;  // 0..1 (M half: rows wm*128..)
  const int wn = w & 3;   // 0..3 (N quarter: cols wn*64..)

  // XCD-aware bijective swizzle (nwg = 256)
  const int bid = blockIdx.x;
  const int swz = (bid & 7) * 32 + (bid >> 3);
  const int bm = swz >> 3;
  const int bn_ = swz & 7;
  const long tileM = (long)bm * 256;
  const long tileN = (long)bn_ * 256;

  // fragment read addresses (bytes). Lane reads row (l&31) of its 32-row block,
  // k-chunk ks*2 + (l>>5), stored at slot ^ ((row>>1)&3).
  const int kc = l >> 5;          // 0..1
  const int key = (l >> 1) & 3;   // swizzle key (row low bits = l&31)
  const unsigned ldsb = (unsigned)(uintptr_t)(lds_s3*)&lds[0];
  const unsigned aAd0 = ldsb + (unsigned)((wm * 128 + (l & 31)) * 64 + ((kc ^ key) * 16));
  const unsigned aAd1 = ldsb + (unsigned)((wm * 128 + (l & 31)) * 64 + (((kc + 2) ^ key) * 16));
  const unsigned bAd0 = ldsb + 65536u + (unsigned)((wn * 64 + (l & 31)) * 64 + ((kc ^ key) * 16));
  const unsigned bAd1 = ldsb + 65536u + (unsigned)((wn * 64 + (l & 31)) * 64 + (((kc + 2) ^ key) * 16));

  // staging: thread t -> LDS t*16B (+8KB for rows 128..255); global source
  // row = t>>2 (and +128), k-slot = (t&3) ^ ((t>>3)&3)  [key=(row>>1)&3]
  const int sdst = tid * 8; // shorts
  const int sslot = ((tid & 3) ^ ((tid >> 3) & 3)) * 8;
  const short* aLo = A + (tileM + (tid >> 2)) * (long)K_TOTAL + sslot;
  const short* aHi = aLo + 128 * (long)K_TOTAL;
  const short* bLo = B + (tileN + (tid >> 2)) * (long)K_TOTAL + sslot;
  const short* bHi = bLo + 128 * (long)K_TOTAL;

  f32x16 acc[4][2];
#pragma unroll
  for (int mb = 0; mb < 4; ++mb)
#pragma unroll
    for (int nb = 0; nb < 2; ++nb)
#pragma unroll
      for (int r = 0; r < 16; ++r)
        acc[mb][nb][r] = 0.f;

  short8 am[4][2], bn[2][2];

  // prologue: stage tiles 0,1,2; vmcnt(4) validates 0,1; issue tile-0 reads
  // in steady-state order (am01, bn, am23)
  STAGET(0, 0);
  STAGET(1, 32);
  STAGET(2, 64);
  SBAR;
  asm volatile("s_waitcnt vmcnt(4)");
  BAR;
  RD_AM01(0);
  RD_BN(0);
  RD_AM23(0);
  SBAR;

  // main: t = 0..251 (stages tiles 3..254; preloads buffer (t+1)&3)
  for (int t4 = 0; t4 < 252; t4 += 4) {
    KT(true, 3, (t4 + 3) * 32, true, 1, FEN4);
    KT(true, 0, (t4 + 4) * 32, true, 2, FEN4);
    KT(true, 1, (t4 + 5) * 32, true, 3, FEN4);
    KT(true, 2, (t4 + 6) * 32, true, 0, FEN4);
  }
  // t=252: stage 255; t=253: FEN0 validates 255; t=254: preload 255; t=255: compute
  KT(true, 3, 255 * 32, true, 1, FEN4);
  KT(false, 0, 0, true, 2, FEN0);
  KT(false, 0, 0, true, 3, FNOP);
  KT(false, 0, 0, false, 0, FNOP);

  // epilogue: C = acc + bias. 32x32 C/D map: col = l&31,
  // row = (reg&3) + 8*(reg>>2) + 4*(l>>5)  [m74/m101 verified]
  const int rbase = (int)tileM + wm * 128 + 4 * kc;
  const int cbase = (int)tileN + wn * 64 + (l & 31);
#pragma unroll
  for (int mb = 0; mb < 4; ++mb)
#pragma unroll
    for (int nb = 0; nb < 2; ++nb) {
      const float bv = bias[cbase + nb * 32];
#pragma unroll
      for (int r = 0; r < 16; ++r) {
        const int row = rbase + mb * 32 + (r & 3) + 8 * (r >> 2);
        C[(long)row * N_TOTAL + cbase + nb * 32] = acc[mb][nb][r] + bv;
      }
    }
}

extern "C" void kernel_launch(void* const* d_in, const int* in_sizes, int n_in,
                              void* d_out, int out_size, void* d_ws, size_t ws_size,
                              hipStream_t stream) {
  const float* x = (const float*)d_in[0];
  const float* W = (const float*)d_in[1];
  const float* bias = (const float*)d_in[2];
  float* out = (float*)d_out;

  short* xb = (short*)d_ws;                                          // 134 MB
  short* wh = (short*)((char*)d_ws + (size_t)M_TOTAL * K_TOTAL * 2); // 33.5 MB

  cvt_x_kernel<<<2048, 256, 0, stream>>>(x, xb, (long)M_TOTAL * K_TOTAL);
  fwht_w_kernel<<<N_TOTAL, 256, 0, stream>>>(W, wh);

  const int grid = (M_TOTAL / 256) * (N_TOTAL / 256); // 256
  gemm_kernel<<<grid, 512, 0, stream>>>(xb, wh, bias, out);
}

// Round 13
// 357.620 us; speedup vs baseline: 1.0518x; 1.0518x over previous
//
#include <hip/hip_runtime.h>
#include <hip/hip_bf16.h>
#include <stdint.h>

// out = x @ W'^T + bias, W' = FWHT(W rows)/sqrt(n)  (H symmetric, folded into W)
// x (4,2048,8192) f32 -> M=8192, K=8192 ; W (2048,8192) -> N=2048 ; out f32.

#define M_TOTAL 8192
#define K_TOTAL 8192
#define N_TOTAL 2048
#define D_IN 8192

typedef __attribute__((ext_vector_type(8))) short short8;
typedef __attribute__((ext_vector_type(4))) float f32x4;

typedef __attribute__((address_space(1))) void void_g;
typedef __attribute__((address_space(3))) void void_l;
typedef __attribute__((address_space(3))) short lds_s3;

__device__ __forceinline__ short f2bf(float f) {
  __hip_bfloat16 h = __float2bfloat16(f);
  return *reinterpret_cast<short*>(&h);
}

// ---------------- kernel 1: x fp32 -> bf16 ----------------
__global__ void cvt_x_kernel(const float* __restrict__ x, short* __restrict__ xb, long n) {
  long stride = (long)gridDim.x * blockDim.x * 8;
  for (long i = ((long)blockIdx.x * blockDim.x + threadIdx.x) * 8; i < n; i += stride) {
    float4 v0 = *(const float4*)(x + i);
    float4 v1 = *(const float4*)(x + i + 4);
    short8 o;
    o[0] = f2bf(v0.x); o[1] = f2bf(v0.y); o[2] = f2bf(v0.z); o[3] = f2bf(v0.w);
    o[4] = f2bf(v1.x); o[5] = f2bf(v1.y); o[6] = f2bf(v1.z); o[7] = f2bf(v1.w);
    *(short8*)(xb + i) = o;
  }
}

// ---------------- kernel 2: W' = FWHT(W rows) / sqrt(n), bf16 ----------------
__global__ void fwht_w_kernel(const float* __restrict__ W, short* __restrict__ Wh) {
  __shared__ float buf[D_IN];
  const int row = blockIdx.x;
  const float* src = W + (long)row * D_IN;
  for (int i = threadIdx.x; i < D_IN / 4; i += blockDim.x)
    ((float4*)buf)[i] = ((const float4*)src)[i];
  for (int h = 1; h < D_IN; h <<= 1) {
    __syncthreads();
    for (int p = threadIdx.x; p < D_IN / 2; p += blockDim.x) {
      int i = ((p & ~(h - 1)) << 1) | (p & (h - 1));
      float a = buf[i], b = buf[i + h];
      buf[i] = a + b;
      buf[i + h] = a - b;
    }
  }
  __syncthreads();
  const float s = 0.011048543456039806f; // 1/sqrt(8192)
  short* dst = Wh + (long)row * D_IN;
  for (int i = threadIdx.x; i < D_IN; i += blockDim.x)
    dst[i] = f2bf(buf[i] * s);
}

// ---------------- kernel 3: 256x256, BK=32, ring-5, fence per 2 tiles -----------
// R11 base (coalesced XOR-swizzled staging, free-run tile body, counted lgkm
// ledger, 16x16x32 MFMA -- 1127-1180 TF / 51%) with ONE change: barrier cadence
// halved. Ring-5 (160 KiB LDS, full CU), staging 4 tiles ahead, ONE fused
// {vmcnt(4); s_barrier} per 2 K-tiles (at odd tiles). Fence at odd T drains
// stages older than {T-1's,T's} -> validates bufs <= T+3; reads during T+1/T+2
// target T+2/T+3 (valid). WAR: each buf overwrite is >= 1 full tile AND one
// barrier after that buf's last read-issue. Tail: fence@251 vmcnt(4) validates
// <=254; fence@253 vmcnt(0) validates 255. ds_read 16-bit offset limit handled
// via lo(bufs 0-2)/hi(bufs 3-4) base regs.
#define NKT 256 // K-tiles of 32

#define ABUF(b) ((b) * 8192)            // shorts
#define BBUF(b) (40960 + (b) * 8192)    // shorts (B region at byte 81920)

#define SBAR __builtin_amdgcn_sched_barrier(0)
#define BAR __builtin_amdgcn_s_barrier()
#define FEN4 do { SBAR; asm volatile("s_waitcnt vmcnt(4)"); BAR; } while (0)
#define FEN0 do { SBAR; asm volatile("s_waitcnt vmcnt(0)"); BAR; } while (0)
#define FNOP do { } while (0)

// stage one K-tile (A + B, 4 x global_load_lds w16 per thread)
#define STAGET(PB, KOFF)                                                                          \
  __builtin_amdgcn_global_load_lds((void_g*)(aLo + (KOFF)),                                       \
                                   (void_l*)&lds[ABUF(PB) + sdst], 16, 0, 0);                     \
  __builtin_amdgcn_global_load_lds((void_g*)(aHi + (KOFF)),                                       \
                                   (void_l*)&lds[ABUF(PB) + sdst + 4096], 16, 0, 0);              \
  __builtin_amdgcn_global_load_lds((void_g*)(bLo + (KOFF)),                                       \
                                   (void_l*)&lds[BBUF(PB) + sdst], 16, 0, 0);                     \
  __builtin_amdgcn_global_load_lds((void_g*)(bHi + (KOFF)),                                       \
                                   (void_l*)&lds[BBUF(PB) + sdst + 4096], 16, 0, 0);

#define DSR(dst, ADDR, IMM)                                                                       \
  asm volatile("ds_read_b128 %0, %1 offset:%2" : "=v"(dst) : "v"(ADDR), "i"(IMM))

// base/immediate split (16-bit ds offset): bufs 0-2 via Lo, 3-4 via Hi(+49152B)
#define ABASE(NB) ((NB) < 3 ? aAdLo : aAdHi)
#define BBASE(NB) ((NB) < 3 ? bAdLo : bAdHi)
#define BIMM(NB)  ((((NB) < 3 ? (NB) : (NB) - 3)) * 16384)

#define RD_AM03(NB)                                                                               \
  DSR(am[0], ABASE(NB), BIMM(NB) + 0);    DSR(am[1], ABASE(NB), BIMM(NB) + 1024);                 \
  DSR(am[2], ABASE(NB), BIMM(NB) + 2048); DSR(am[3], ABASE(NB), BIMM(NB) + 3072);
#define RD_BN(NB)                                                                                 \
  DSR(bn[0], BBASE(NB), BIMM(NB) + 0);    DSR(bn[1], BBASE(NB), BIMM(NB) + 1024);                 \
  DSR(bn[2], BBASE(NB), BIMM(NB) + 2048); DSR(bn[3], BBASE(NB), BIMM(NB) + 3072);
#define RD_AM47(NB)                                                                               \
  DSR(am[4], ABASE(NB), BIMM(NB) + 4096); DSR(am[5], ABASE(NB), BIMM(NB) + 5120);                 \
  DSR(am[6], ABASE(NB), BIMM(NB) + 6144); DSR(am[7], ABASE(NB), BIMM(NB) + 7168);

#define MFQ(MIB)                                                                                  \
  __builtin_amdgcn_s_setprio(1);                                                                  \
  _Pragma("unroll") for (int mi = 0; mi < 4; ++mi) {                                              \
    _Pragma("unroll") for (int nj = 0; nj < 4; ++nj)                                              \
        acc[(MIB) + mi][nj] = __builtin_amdgcn_mfma_f32_16x16x32_bf16(                            \
            am[(MIB) + mi], bn[nj], acc[(MIB) + mi][nj], 0, 0, 0);                                \
  }                                                                                               \
  __builtin_amdgcn_s_setprio(0);

// one K-tile. DOSTG: stage into slot PB at KOFF. DOPRE: preload buffer NB.
// FEN: FEN4 / FEN0 / FNOP (fences only at odd tiles).
#define KT(DOSTG, PB, KOFF, DOPRE, NB, FEN)                                                       \
  {                                                                                               \
    asm volatile("s_waitcnt lgkmcnt(4)");                                                         \
    SBAR;                                                                                         \
    MFQ(0);                                                                                       \
    SBAR;                                                                                         \
    if (DOSTG) { STAGET(PB, KOFF); }                                                              \
    if (DOPRE) { RD_AM03(NB); }                                                                   \
    SBAR;                                                                                         \
    if (DOPRE) { asm volatile("s_waitcnt lgkmcnt(4)"); }                                          \
    else       { asm volatile("s_waitcnt lgkmcnt(0)"); }                                          \
    SBAR;                                                                                         \
    MFQ(4);                                                                                       \
    SBAR;                                                                                         \
    if (DOPRE) { RD_BN(NB); RD_AM47(NB); }                                                        \
    SBAR;                                                                                         \
    FEN;                                                                                          \
  }

__global__ __launch_bounds__(512, 2) void gemm_kernel(const short* __restrict__ A,
                                                      const short* __restrict__ B,
                                                      const float* __restrict__ bias,
                                                      float* __restrict__ C) {
  __shared__ __attribute__((aligned(16))) short lds[81920]; // 160 KiB (ring-5)

  const int tid = threadIdx.x;
  const int l = tid & 63;
  const int w = tid >> 6;
  const int wm = w >> 2;  // 0..1 (M half: rows wm*128..)
  const int wn = w & 3;   // 0..3 (N quarter: rows wn*64..)

  // XCD-aware bijective swizzle (nwg = 256)
  const int bid = blockIdx.x;
  const int swz = (bid & 7) * 32 + (bid >> 3);
  const int bm = swz >> 3;
  const int bn_ = swz & 7;
  const long tileM = (long)bm * 256;
  const long tileN = (long)bn_ * 256;

  // fragment read addresses: row = (wave rows) + (l&15); k-slot = l>>4, stored
  // at slot ^ ((row>>1)&3) = slot ^ ((l>>1)&3)
  const int kx = (((l >> 4) ^ ((l >> 1) & 3)) * 8); // shorts
  const int rb = (l & 15) * 32;                     // shorts
  const unsigned ldsbase = (unsigned)(uintptr_t)(lds_s3*)&lds[0];
  const unsigned aAdLo = ldsbase + (unsigned)(wm * 4096 + rb + kx) * 2u;
  const unsigned aAdHi = aAdLo + 49152u;
  const unsigned bAdLo = ldsbase + 81920u + (unsigned)(wn * 2048 + rb + kx) * 2u;
  const unsigned bAdHi = bAdLo + 49152u;

  // staging: thread t -> LDS t*16B (+8KB for rows 128..255); global source
  // row = t>>2 (and +128), k-slot = (t&3) ^ ((t>>3)&3)  [key=(row>>1)&3]
  const int sdst = tid * 8; // shorts
  const int sslot = ((tid & 3) ^ ((tid >> 3) & 3)) * 8;
  const short* aLo = A + (tileM + (tid >> 2)) * (long)K_TOTAL + sslot;
  const short* aHi = aLo + 128 * (long)K_TOTAL;
  const short* bLo = B + (tileN + (tid >> 2)) * (long)K_TOTAL + sslot;
  const short* bHi = bLo + 128 * (long)K_TOTAL;

  f32x4 acc[8][4];
#pragma unroll
  for (int mi = 0; mi < 8; ++mi)
#pragma unroll
    for (int nj = 0; nj < 4; ++nj)
      acc[mi][nj] = (f32x4){0.f, 0.f, 0.f, 0.f};

  short8 am[8], bn[4];

  // prologue: stage tiles 0-3 (16 loads); vmcnt(4) validates 0,1,2; preload 0
  STAGET(0, 0);
  STAGET(1, 32);
  STAGET(2, 64);
  STAGET(3, 96);
  SBAR;
  asm volatile("s_waitcnt vmcnt(4)");
  BAR;
  RD_AM03(0);
  RD_BN(0);
  RD_AM47(0);
  SBAR;

  // main: 25 super-blocks of 10 tiles (t = 0..249); stage t+4; preload t+1;
  // fence (vmcnt(4)+barrier) at odd tiles only
  for (int t0 = 0; t0 < 250; t0 += 10) {
    KT(true, 4, (t0 + 4) * 32, true, 1, FNOP);
    KT(true, 0, (t0 + 5) * 32, true, 2, FEN4);
    KT(true, 1, (t0 + 6) * 32, true, 3, FNOP);
    KT(true, 2, (t0 + 7) * 32, true, 4, FEN4);
    KT(true, 3, (t0 + 8) * 32, true, 0, FNOP);
    KT(true, 4, (t0 + 9) * 32, true, 1, FEN4);
    KT(true, 0, (t0 + 10) * 32, true, 2, FNOP);
    KT(true, 1, (t0 + 11) * 32, true, 3, FEN4);
    KT(true, 2, (t0 + 12) * 32, true, 4, FNOP);
    KT(true, 3, (t0 + 13) * 32, true, 0, FEN4);
  }
  // tail tiles 250..255
  KT(true, 4, 254 * 32, true, 1, FNOP);  // 250
  KT(true, 0, 255 * 32, true, 2, FEN4);  // 251: validates <=254
  KT(false, 0, 0, true, 3, FNOP);        // 252
  KT(false, 0, 0, true, 4, FEN0);        // 253: validates 255
  KT(false, 0, 0, true, 0, FNOP);        // 254: preload 255
  KT(false, 0, 0, false, 0, FNOP);       // 255: compute only

  // epilogue: C = acc + bias  (C/D map: col = l&15, row = (l>>4)*4 + reg)
  const int rb0 = (int)tileM + wm * 128 + (l >> 4) * 4;
  const int cb = (int)tileN + wn * 64 + (l & 15);
#pragma unroll
  for (int mi = 0; mi < 8; ++mi)
#pragma unroll
    for (int nj = 0; nj < 4; ++nj) {
      float bv = bias[cb + nj * 16];
      const int r0 = rb0 + mi * 16;
#pragma unroll
      for (int r = 0; r < 4; ++r)
        C[(long)(r0 + r) * N_TOTAL + cb + nj * 16] = acc[mi][nj][r] + bv;
    }
}

extern "C" void kernel_launch(void* const* d_in, const int* in_sizes, int n_in,
                              void* d_out, int out_size, void* d_ws, size_t ws_size,
                              hipStream_t stream) {
  const float* x = (const float*)d_in[0];
  const float* W = (const float*)d_in[1];
  const float* bias = (const float*)d_in[2];
  float* out = (float*)d_out;

  short* xb = (short*)d_ws;                                          // 134 MB
  short* wh = (short*)((char*)d_ws + (size_t)M_TOTAL * K_TOTAL * 2); // 33.5 MB

  cvt_x_kernel<<<2048, 256, 0, stream>>>(x, xb, (long)M_TOTAL * K_TOTAL);
  fwht_w_kernel<<<N_TOTAL, 256, 0, stream>>>(W, wh);

  const int grid = (M_TOTAL / 256) * (N_TOTAL / 256); // 256
  gemm_kernel<<<grid, 512, 0, stream>>>(xb, wh, bias, out);
}

// Round 14
// 336.452 us; speedup vs baseline: 1.1180x; 1.0629x over previous
//
#include <hip/hip_runtime.h>
#include <hip/hip_bf16.h>
#include <stdint.h>

// out = x @ W'^T + bias, W' = FWHT(W rows)/sqrt(n)  (H symmetric, folded into W)
// x (4,2048,8192) f32 -> M=8192, K=8192 ; W (2048,8192) -> N=2048 ; out f32.

#define M_TOTAL 8192
#define K_TOTAL 8192
#define N_TOTAL 2048
#define D_IN 8192

typedef __attribute__((ext_vector_type(8))) short short8;
typedef __attribute__((ext_vector_type(4))) float f32x4;

typedef __attribute__((address_space(1))) void void_g;
typedef __attribute__((address_space(3))) void void_l;
typedef __attribute__((address_space(3))) short lds_s3;

__device__ __forceinline__ short f2bf(float f) {
  __hip_bfloat16 h = __float2bfloat16(f);
  return *reinterpret_cast<short*>(&h);
}

// ---------------- kernel 1: x fp32 -> bf16 ----------------
__global__ void cvt_x_kernel(const float* __restrict__ x, short* __restrict__ xb, long n) {
  long stride = (long)gridDim.x * blockDim.x * 8;
  for (long i = ((long)blockIdx.x * blockDim.x + threadIdx.x) * 8; i < n; i += stride) {
    float4 v0 = *(const float4*)(x + i);
    float4 v1 = *(const float4*)(x + i + 4);
    short8 o;
    o[0] = f2bf(v0.x); o[1] = f2bf(v0.y); o[2] = f2bf(v0.z); o[3] = f2bf(v0.w);
    o[4] = f2bf(v1.x); o[5] = f2bf(v1.y); o[6] = f2bf(v1.z); o[7] = f2bf(v1.w);
    *(short8*)(xb + i) = o;
  }
}

// ---------------- kernel 2: W' = FWHT(W rows) / sqrt(n), bf16 ----------------
__global__ void fwht_w_kernel(const float* __restrict__ W, short* __restrict__ Wh) {
  __shared__ float buf[D_IN];
  const int row = blockIdx.x;
  const float* src = W + (long)row * D_IN;
  for (int i = threadIdx.x; i < D_IN / 4; i += blockDim.x)
    ((float4*)buf)[i] = ((const float4*)src)[i];
  for (int h = 1; h < D_IN; h <<= 1) {
    __syncthreads();
    for (int p = threadIdx.x; p < D_IN / 2; p += blockDim.x) {
      int i = ((p & ~(h - 1)) << 1) | (p & (h - 1));
      float a = buf[i], b = buf[i + h];
      buf[i] = a + b;
      buf[i + h] = a - b;
    }
  }
  __syncthreads();
  const float s = 0.011048543456039806f; // 1/sqrt(8192)
  short* dst = Wh + (long)row * D_IN;
  for (int i = threadIdx.x; i < D_IN; i += blockDim.x)
    dst[i] = f2bf(buf[i] * s);
}

// ---------------- kernel 3: 256x256 8-phase GEMM, coalesced XOR-swizzled LDS ----
// R7's 8-phase schedule (BK=64, 2-dbuf, per-phase barriers, vmcnt(4)/K-tile,
// lgkm(8) stagger -- refcheck'd) x R10's coalesced staging. Halves = [128 rows]
// [64 k] bf16 row-major, 16B-chunk XOR swizzle: chunk c of row r stored at slot
// c ^ (r&7). Staging: thread t -> linear LDS chunk t (row t>>3, slot t&7),
// global source chunk (t&7)^((t>>3)&7): 8 lanes cover one full 128B row ->
// COALESCED (fixes R7's 4x-scattered sources). Reads apply the same XOR ->
// per-quarter-wave 2 lanes/slot = free. ks0/ks1 chunk differs by XOR 4 ->
// two base regs (aAd1 = aAd0 ^ 64). Frag imm = D*32768 + mi*2048.
#define NT 128 // K-tiles of 64

#define ADST(D, H) (((D) * 2 + (H)) * 8192 + sdst)          // shorts
#define BDST(D, H) (32768 + ((D) * 2 + (H)) * 8192 + sdst)  // shorts

// stage one half-tile: 2 x global_load_lds w16; 2nd covers rows 64..127
#define STG(DST, SRC, KOFF)                                                                       \
  __builtin_amdgcn_global_load_lds((void_g*)((SRC) + (KOFF)), (void_l*)&lds[DST], 16, 0, 0);      \
  __builtin_amdgcn_global_load_lds((void_g*)((SRC) + (KOFF) + 64 * (long)K_TOTAL),                \
                                   (void_l*)&lds[(DST) + 4096], 16, 0, 0);

#define DSR(dst, ADDR, IMM)                                                                       \
  asm volatile("ds_read_b128 %0, %1 offset:%2" : "=v"(dst) : "v"(ADDR), "i"(IMM))

#define RD_A4(D, MIB)                                                                             \
  DSR(am[0][0], aAd0, (D) * 32768 + ((MIB) + 0) * 2048);                                          \
  DSR(am[0][1], aAd1, (D) * 32768 + ((MIB) + 0) * 2048);                                          \
  DSR(am[1][0], aAd0, (D) * 32768 + ((MIB) + 1) * 2048);                                          \
  DSR(am[1][1], aAd1, (D) * 32768 + ((MIB) + 1) * 2048);                                          \
  DSR(am[2][0], aAd0, (D) * 32768 + ((MIB) + 2) * 2048);                                          \
  DSR(am[2][1], aAd1, (D) * 32768 + ((MIB) + 2) * 2048);                                          \
  DSR(am[3][0], aAd0, (D) * 32768 + ((MIB) + 3) * 2048);                                          \
  DSR(am[3][1], aAd1, (D) * 32768 + ((MIB) + 3) * 2048);

#define RD_B2(D, NJB)                                                                             \
  DSR(bn[(NJB) + 0][0], bAd0, (D) * 32768 + ((NJB) + 0) * 2048);                                  \
  DSR(bn[(NJB) + 0][1], bAd1, (D) * 32768 + ((NJB) + 0) * 2048);                                  \
  DSR(bn[(NJB) + 1][0], bAd0, (D) * 32768 + ((NJB) + 1) * 2048);                                  \
  DSR(bn[(NJB) + 1][1], bAd1, (D) * 32768 + ((NJB) + 1) * 2048);

#define MF(MIB, NJB)                                                                              \
  __builtin_amdgcn_s_setprio(1);                                                                  \
  _Pragma("unroll") for (int mi = 0; mi < 4; ++mi) {                                              \
    _Pragma("unroll") for (int nj = 0; nj < 2; ++nj) {                                            \
      _Pragma("unroll") for (int ks = 0; ks < 2; ++ks) acc[(MIB) + mi][(NJB) + nj] =              \
          __builtin_amdgcn_mfma_f32_16x16x32_bf16(am[mi][ks], bn[(NJB) + nj][ks],                 \
                                                  acc[(MIB) + mi][(NJB) + nj], 0, 0, 0);          \
    }                                                                                             \
  }                                                                                               \
  __builtin_amdgcn_s_setprio(0);

#define BAR __builtin_amdgcn_s_barrier()
#define SBAR __builtin_amdgcn_sched_barrier(0)
#define LG0 do { asm volatile("s_waitcnt lgkmcnt(0)"); SBAR; } while (0)

// one K-tile (4 phases). D: dbuf; STGA/STGB bools; KA/KB k-offsets (shorts);
// FN "4"/"0"; DOF: emit vmcnt fence; LB: trailing barrier.
#define KTILE(D, STGA, KA, STGB, KB, FN, DOF, LB)                                                 \
  {                                                                                               \
    /* ph1: (mi0-3 x nj0-1) */                                                                    \
    RD_B2(D, 0);                                                                                  \
    RD_A4(D, 0);                                                                                  \
    if (STGA) { STG(ADST(D ^ 1, 0), aSrc0, KA); }                                                 \
    asm volatile("s_waitcnt lgkmcnt(8)");                                                         \
    BAR;                                                                                          \
    LG0;                                                                                          \
    MF(0, 0);                                                                                     \
    BAR;                                                                                          \
    /* ph2: (mi0-3 x nj2-3) */                                                                    \
    RD_B2(D, 2);                                                                                  \
    if (STGA) { STG(ADST(D ^ 1, 1), aSrc1, KA); }                                                 \
    BAR;                                                                                          \
    LG0;                                                                                          \
    MF(0, 2);                                                                                     \
    BAR;                                                                                          \
    /* ph3: (mi4-7 x nj0-1) */                                                                    \
    RD_A4(D, 4);                                                                                  \
    if (STGB) { STG(BDST(D, 0), bSrc0, KB); }                                                     \
    BAR;                                                                                          \
    LG0;                                                                                          \
    MF(4, 0);                                                                                     \
    BAR;                                                                                          \
    /* ph4: (mi4-7 x nj2-3), fence */                                                             \
    if (STGB) { STG(BDST(D, 1), bSrc1, KB); }                                                     \
    BAR;                                                                                          \
    MF(4, 2);                                                                                     \
    if (DOF) { asm volatile("s_waitcnt vmcnt(" FN ")"); }                                         \
    if (LB) BAR;                                                                                  \
  }

__global__ __launch_bounds__(512, 2) void gemm_kernel(const short* __restrict__ A,
                                                      const short* __restrict__ B,
                                                      const float* __restrict__ bias,
                                                      float* __restrict__ C) {
  __shared__ __attribute__((aligned(16))) short lds[65536]; // 128 KiB

  const int tid = threadIdx.x;
  const int l = tid & 63;
  const int w = tid >> 6;
  const int wm = w >> 2;   // 0..1 (M half)
  const int wn = w & 3;    // 0..3 (N quarter)
  const int wh = wn >> 1;  // B half

  // XCD-aware bijective swizzle (nwg = 256)
  const int bid = blockIdx.x;
  const int swz = (bid & 7) * 32 + (bid >> 3);
  const int bm = swz >> 3;
  const int bn_ = swz & 7;
  const long tileM = (long)bm * 256;
  const long tileN = (long)bn_ * 256;

  // read bases (bytes): row-in-frag = l&15, slot0 = (l>>4) ^ (l&7); ks1 = ^64
  const int slot0 = (l >> 4) ^ (l & 7);
  const int laneb = (l & 15) * 128 + slot0 * 16;
  const unsigned ldsb = (unsigned)(uintptr_t)(lds_s3*)&lds[0];
  const unsigned aAd0 = ldsb + (unsigned)(wm * 16384 + laneb);
  const unsigned aAd1 = aAd0 ^ 64u;
  const unsigned bAd0 = ldsb + 65536u + (unsigned)(wh * 16384 + (wn & 1) * 8192 + laneb);
  const unsigned bAd1 = bAd0 ^ 64u;

  // staging: thread t -> LDS chunk t (row t>>3, slot t&7); global source chunk
  // (t&7)^((t>>3)&7) of row t>>3 (and +64 rows for the second load)
  const int sdst = tid * 8; // shorts
  const int srow = tid >> 3;
  const int sslot = ((tid & 7) ^ (srow & 7)) * 8; // shorts
  const short* aSrc0 = A + (tileM + srow) * (long)K_TOTAL + sslot;
  const short* aSrc1 = aSrc0 + 128 * (long)K_TOTAL;
  const short* bSrc0 = B + (tileN + srow) * (long)K_TOTAL + sslot;
  const short* bSrc1 = bSrc0 + 128 * (long)K_TOTAL;

  f32x4 acc[8][4];
#pragma unroll
  for (int mi = 0; mi < 8; ++mi)
#pragma unroll
    for (int nj = 0; nj < 4; ++nj)
      acc[mi][nj] = (f32x4){0.f, 0.f, 0.f, 0.f};

  // prologue: A(0)->d0, B(0)->d0, B(1)->d1 (12 loads); vmcnt(4) leaves B(1)
  STG(ADST(0, 0), aSrc0, 0);
  STG(ADST(0, 1), aSrc1, 0);
  STG(BDST(0, 0), bSrc0, 0);
  STG(BDST(0, 1), bSrc1, 0);
  STG(BDST(1, 0), bSrc0, 64);
  STG(BDST(1, 1), bSrc1, 64);
  asm volatile("s_waitcnt vmcnt(4)");
  BAR;

  short8 am[4][2], bn[4][2];

  // main: t = 0,2,...,124; even tile stages A(t+1)->d1, B(t+2)->d0;
  // odd tile stages A(t+2)->d0, B(t+3)->d1
  for (int t = 0; t < NT - 2; t += 2) {
    KTILE(0, true, (t + 1) * 64, true, (t + 2) * 64, "4", true, true);
    KTILE(1, true, (t + 2) * 64, true, (t + 3) * 64, "4", true, true);
  }
  // tail: t=126 stages A(127), drains; t=127 compute-only
  KTILE(0, true, 127 * 64, false, 0, "0", true, true);
  KTILE(1, false, 0, false, 0, "0", false, false);

  // epilogue: C = acc + bias  (C/D map: col = l&15, row = (l>>4)*4 + reg)
  const int rb = (int)tileM + wm * 128 + (l >> 4) * 4;
  const int cb = (int)tileN + wn * 64 + (l & 15);
#pragma unroll
  for (int mi = 0; mi < 8; ++mi)
#pragma unroll
    for (int nj = 0; nj < 4; ++nj) {
      float bv = bias[cb + nj * 16];
      const int r0 = rb + mi * 16;
#pragma unroll
      for (int r = 0; r < 4; ++r)
        C[(long)(r0 + r) * N_TOTAL + cb + nj * 16] = acc[mi][nj][r] + bv;
    }
}

extern "C" void kernel_launch(void* const* d_in, const int* in_sizes, int n_in,
                              void* d_out, int out_size, void* d_ws, size_t ws_size,
                              hipStream_t stream) {
  const float* x = (const float*)d_in[0];
  const float* W = (const float*)d_in[1];
  const float* bias = (const float*)d_in[2];
  float* out = (float*)d_out;

  short* xb = (short*)d_ws;                                          // 134 MB
  short* wh = (short*)((char*)d_ws + (size_t)M_TOTAL * K_TOTAL * 2); // 33.5 MB

  cvt_x_kernel<<<2048, 256, 0, stream>>>(x, xb, (long)M_TOTAL * K_TOTAL);
  fwht_w_kernel<<<N_TOTAL, 256, 0, stream>>>(W, wh);

  const int grid = (M_TOTAL / 256) * (N_TOTAL / 256); // 256
  gemm_kernel<<<grid, 512, 0, stream>>>(xb, wh, bias, out);
}

// Round 15
// 328.251 us; speedup vs baseline: 1.1459x; 1.0250x over previous
//
#include <hip/hip_runtime.h>
#include <hip/hip_bf16.h>
#include <stdint.h>

// out = x @ W'^T + bias, W' = FWHT(W rows)/sqrt(n)  (H symmetric, folded into W)
// x (4,2048,8192) f32 -> M=8192, K=8192 ; W (2048,8192) -> N=2048 ; out f32.

#define M_TOTAL 8192
#define K_TOTAL 8192
#define N_TOTAL 2048
#define D_IN 8192

typedef __attribute__((ext_vector_type(8))) short short8;
typedef __attribute__((ext_vector_type(4))) float f32x4;

typedef __attribute__((address_space(1))) void void_g;
typedef __attribute__((address_space(3))) void void_l;
typedef __attribute__((address_space(3))) short lds_s3;

__device__ __forceinline__ short f2bf(float f) {
  __hip_bfloat16 h = __float2bfloat16(f);
  return *reinterpret_cast<short*>(&h);
}

// ---------------- kernel 1: fused prep (cvt_x || fwht_w, concurrent) ------------
// Blocks 0..2047: grid-stride f32->bf16 conversion of x (HBM-bound, ~6 TB/s).
// Blocks 2048..4095: FWHT one W row in 32KB LDS + scale + bf16 (LDS-bound).
// Disjoint data, complementary pipes -> co-scheduled across CUs, prep ~= max
// of the two instead of their sum (saves the ~25us fwht serialization).
__global__ __launch_bounds__(256) void prep_kernel(const float* __restrict__ x,
                                                   short* __restrict__ xb,
                                                   const float* __restrict__ W,
                                                   short* __restrict__ wh) {
  __shared__ float buf[D_IN];
  const int b = blockIdx.x;
  if (b < 2048) {
    // ---- cvt path ----
    const long n = (long)M_TOTAL * K_TOTAL;
    const long stride = (long)2048 * 256 * 8;
    for (long i = ((long)b * 256 + threadIdx.x) * 8; i < n; i += stride) {
      float4 v0 = *(const float4*)(x + i);
      float4 v1 = *(const float4*)(x + i + 4);
      short8 o;
      o[0] = f2bf(v0.x); o[1] = f2bf(v0.y); o[2] = f2bf(v0.z); o[3] = f2bf(v0.w);
      o[4] = f2bf(v1.x); o[5] = f2bf(v1.y); o[6] = f2bf(v1.z); o[7] = f2bf(v1.w);
      *(short8*)(xb + i) = o;
    }
  } else {
    // ---- fwht path ----
    const int row = b - 2048;
    const float* src = W + (long)row * D_IN;
    for (int i = threadIdx.x; i < D_IN / 4; i += blockDim.x)
      ((float4*)buf)[i] = ((const float4*)src)[i];
    for (int h = 1; h < D_IN; h <<= 1) {
      __syncthreads();
      for (int p = threadIdx.x; p < D_IN / 2; p += blockDim.x) {
        int i = ((p & ~(h - 1)) << 1) | (p & (h - 1));
        float a = buf[i], bb = buf[i + h];
        buf[i] = a + bb;
        buf[i + h] = a - bb;
      }
    }
    __syncthreads();
    const float s = 0.011048543456039806f; // 1/sqrt(8192)
    short* dst = wh + (long)row * D_IN;
    for (int i = threadIdx.x; i < D_IN; i += blockDim.x)
      dst[i] = f2bf(buf[i] * s);
  }
}

// ---------------- kernel 2: 256x256 8-phase GEMM, coalesced XOR-swizzled LDS ----
// R14 gemm, UNCHANGED (230 us, 1196 TF, MfmaUtil 52.9%, 0 bank conflicts):
// 8-phase schedule (BK=64, 2-dbuf, per-phase barriers, vmcnt(4)/K-tile,
// lgkm(8) stagger) with coalesced staging. Halves = [128 rows][64 k] bf16
// row-major, 16B-chunk XOR swizzle: chunk c of row r stored at slot c ^ (r&7).
#define NT 128 // K-tiles of 64

#define ADST(D, H) (((D) * 2 + (H)) * 8192 + sdst)          // shorts
#define BDST(D, H) (32768 + ((D) * 2 + (H)) * 8192 + sdst)  // shorts

#define STG(DST, SRC, KOFF)                                                                       \
  __builtin_amdgcn_global_load_lds((void_g*)((SRC) + (KOFF)), (void_l*)&lds[DST], 16, 0, 0);      \
  __builtin_amdgcn_global_load_lds((void_g*)((SRC) + (KOFF) + 64 * (long)K_TOTAL),                \
                                   (void_l*)&lds[(DST) + 4096], 16, 0, 0);

#define DSR(dst, ADDR, IMM)                                                                       \
  asm volatile("ds_read_b128 %0, %1 offset:%2" : "=v"(dst) : "v"(ADDR), "i"(IMM))

#define RD_A4(D, MIB)                                                                             \
  DSR(am[0][0], aAd0, (D) * 32768 + ((MIB) + 0) * 2048);                                          \
  DSR(am[0][1], aAd1, (D) * 32768 + ((MIB) + 0) * 2048);                                          \
  DSR(am[1][0], aAd0, (D) * 32768 + ((MIB) + 1) * 2048);                                          \
  DSR(am[1][1], aAd1, (D) * 32768 + ((MIB) + 1) * 2048);                                          \
  DSR(am[2][0], aAd0, (D) * 32768 + ((MIB) + 2) * 2048);                                          \
  DSR(am[2][1], aAd1, (D) * 32768 + ((MIB) + 2) * 2048);                                          \
  DSR(am[3][0], aAd0, (D) * 32768 + ((MIB) + 3) * 2048);                                          \
  DSR(am[3][1], aAd1, (D) * 32768 + ((MIB) + 3) * 2048);

#define RD_B2(D, NJB)                                                                             \
  DSR(bn[(NJB) + 0][0], bAd0, (D) * 32768 + ((NJB) + 0) * 2048);                                  \
  DSR(bn[(NJB) + 0][1], bAd1, (D) * 32768 + ((NJB) + 0) * 2048);                                  \
  DSR(bn[(NJB) + 1][0], bAd0, (D) * 32768 + ((NJB) + 1) * 2048);                                  \
  DSR(bn[(NJB) + 1][1], bAd1, (D) * 32768 + ((NJB) + 1) * 2048);

#define MF(MIB, NJB)                                                                              \
  __builtin_amdgcn_s_setprio(1);                                                                  \
  _Pragma("unroll") for (int mi = 0; mi < 4; ++mi) {                                              \
    _Pragma("unroll") for (int nj = 0; nj < 2; ++nj) {                                            \
      _Pragma("unroll") for (int ks = 0; ks < 2; ++ks) acc[(MIB) + mi][(NJB) + nj] =              \
          __builtin_amdgcn_mfma_f32_16x16x32_bf16(am[mi][ks], bn[(NJB) + nj][ks],                 \
                                                  acc[(MIB) + mi][(NJB) + nj], 0, 0, 0);          \
    }                                                                                             \
  }                                                                                               \
  __builtin_amdgcn_s_setprio(0);

#define BAR __builtin_amdgcn_s_barrier()
#define SBAR __builtin_amdgcn_sched_barrier(0)
#define LG0 do { asm volatile("s_waitcnt lgkmcnt(0)"); SBAR; } while (0)

#define KTILE(D, STGA, KA, STGB, KB, FN, DOF, LB)                                                 \
  {                                                                                               \
    RD_B2(D, 0);                                                                                  \
    RD_A4(D, 0);                                                                                  \
    if (STGA) { STG(ADST(D ^ 1, 0), aSrc0, KA); }                                                 \
    asm volatile("s_waitcnt lgkmcnt(8)");                                                         \
    BAR;                                                                                          \
    LG0;                                                                                          \
    MF(0, 0);                                                                                     \
    BAR;                                                                                          \
    RD_B2(D, 2);                                                                                  \
    if (STGA) { STG(ADST(D ^ 1, 1), aSrc1, KA); }                                                 \
    BAR;                                                                                          \
    LG0;                                                                                          \
    MF(0, 2);                                                                                     \
    BAR;                                                                                          \
    RD_A4(D, 4);                                                                                  \
    if (STGB) { STG(BDST(D, 0), bSrc0, KB); }                                                     \
    BAR;                                                                                         \
    LG0;                                                                                          \
    MF(4, 0);                                                                                     \
    BAR;                                                                                          \
    if (STGB) { STG(BDST(D, 1), bSrc1, KB); }                                                     \
    BAR;                                                                                          \
    MF(4, 2);                                                                                     \
    if (DOF) { asm volatile("s_waitcnt vmcnt(" FN ")"); }                                         \
    if (LB) BAR;                                                                                  \
  }

__global__ __launch_bounds__(512, 2) void gemm_kernel(const short* __restrict__ A,
                                                      const short* __restrict__ B,
                                                      const float* __restrict__ bias,
                                                      float* __restrict__ C) {
  __shared__ __attribute__((aligned(16))) short lds[65536]; // 128 KiB

  const int tid = threadIdx.x;
  const int l = tid & 63;
  const int w = tid >> 6;
  const int wm = w >> 2;   // 0..1 (M half)
  const int wn = w & 3;    // 0..3 (N quarter)
  const int wh = wn >> 1;  // B half

  // XCD-aware bijective swizzle (nwg = 256)
  const int bid = blockIdx.x;
  const int swz = (bid & 7) * 32 + (bid >> 3);
  const int bm = swz >> 3;
  const int bn_ = swz & 7;
  const long tileM = (long)bm * 256;
  const long tileN = (long)bn_ * 256;

  // read bases (bytes): row-in-frag = l&15, slot0 = (l>>4) ^ (l&7); ks1 = ^64
  const int slot0 = (l >> 4) ^ (l & 7);
  const int laneb = (l & 15) * 128 + slot0 * 16;
  const unsigned ldsb = (unsigned)(uintptr_t)(lds_s3*)&lds[0];
  const unsigned aAd0 = ldsb + (unsigned)(wm * 16384 + laneb);
  const unsigned aAd1 = aAd0 ^ 64u;
  const unsigned bAd0 = ldsb + 65536u + (unsigned)(wh * 16384 + (wn & 1) * 8192 + laneb);
  const unsigned bAd1 = bAd0 ^ 64u;

  // staging: thread t -> LDS chunk t (row t>>3, slot t&7); global source chunk
  // (t&7)^((t>>3)&7) of row t>>3 (and +64 rows for the second load)
  const int sdst = tid * 8; // shorts
  const int srow = tid >> 3;
  const int sslot = ((tid & 7) ^ (srow & 7)) * 8; // shorts
  const short* aSrc0 = A + (tileM + srow) * (long)K_TOTAL + sslot;
  const short* aSrc1 = aSrc0 + 128 * (long)K_TOTAL;
  const short* bSrc0 = B + (tileN + srow) * (long)K_TOTAL + sslot;
  const short* bSrc1 = bSrc0 + 128 * (long)K_TOTAL;

  f32x4 acc[8][4];
#pragma unroll
  for (int mi = 0; mi < 8; ++mi)
#pragma unroll
    for (int nj = 0; nj < 4; ++nj)
      acc[mi][nj] = (f32x4){0.f, 0.f, 0.f, 0.f};

  // prologue: A(0)->d0, B(0)->d0, B(1)->d1 (12 loads); vmcnt(4) leaves B(1)
  STG(ADST(0, 0), aSrc0, 0);
  STG(ADST(0, 1), aSrc1, 0);
  STG(BDST(0, 0), bSrc0, 0);
  STG(BDST(0, 1), bSrc1, 0);
  STG(BDST(1, 0), bSrc0, 64);
  STG(BDST(1, 1), bSrc1, 64);
  asm volatile("s_waitcnt vmcnt(4)");
  BAR;

  short8 am[4][2], bn[4][2];

  // main: t = 0,2,...,124
  for (int t = 0; t < NT - 2; t += 2) {
    KTILE(0, true, (t + 1) * 64, true, (t + 2) * 64, "4", true, true);
    KTILE(1, true, (t + 2) * 64, true, (t + 3) * 64, "4", true, true);
  }
  // tail: t=126 stages A(127), drains; t=127 compute-only
  KTILE(0, true, 127 * 64, false, 0, "0", true, true);
  KTILE(1, false, 0, false, 0, "0", false, false);

  // epilogue: C = acc + bias  (C/D map: col = l&15, row = (l>>4)*4 + reg)
  const int rb = (int)tileM + wm * 128 + (l >> 4) * 4;
  const int cb = (int)tileN + wn * 64 + (l & 15);
#pragma unroll
  for (int mi = 0; mi < 8; ++mi)
#pragma unroll
    for (int nj = 0; nj < 4; ++nj) {
      float bv = bias[cb + nj * 16];
      const int r0 = rb + mi * 16;
#pragma unroll
      for (int r = 0; r < 4; ++r)
        C[(long)(r0 + r) * N_TOTAL + cb + nj * 16] = acc[mi][nj][r] + bv;
    }
}

extern "C" void kernel_launch(void* const* d_in, const int* in_sizes, int n_in,
                              void* d_out, int out_size, void* d_ws, size_t ws_size,
                              hipStream_t stream) {
  const float* x = (const float*)d_in[0];
  const float* W = (const float*)d_in[1];
  const float* bias = (const float*)d_in[2];
  float* out = (float*)d_out;

  short* xb = (short*)d_ws;                                          // 134 MB
  short* wh = (short*)((char*)d_ws + (size_t)M_TOTAL * K_TOTAL * 2); // 33.5 MB

  prep_kernel<<<4096, 256, 0, stream>>>(x, xb, W, wh);

  const int grid = (M_TOTAL / 256) * (N_TOTAL / 256); // 256
  gemm_kernel<<<grid, 512, 0, stream>>>(xb, wh, bias, out);
}